// Round 5
// baseline (374.873 us; speedup 1.0000x reference)
//
#include <hip/hip_runtime.h>
#include <hip/hip_bf16.h>

#define BN   64
#define MAXN 512
#define DIM  512
#define NH   8
#define NS   32
#define DHD  64
#define NN   32768      // BN*MAXN
#define NE   524288

typedef __hip_bfloat16 bf16;
using bf16x8 = __attribute__((ext_vector_type(8))) short;   // 8 bf16 (4 VGPRs)
using f32x4  = __attribute__((ext_vector_type(4))) float;

// ---- persistent device scratch ----
__device__ int   g_cnt[NN];
__device__ int   g_cur[NN];
__device__ int   g_off[NN + 1];
__device__ int   g_csr[NE];
__device__ float g_dinv[NN];
__device__ bf16  g_xb[NN * DIM];             // 32 MB : x * dinv, bf16
__device__ bf16  g_agg[NN * DIM];            // 32 MB : normalized aggregation
__device__ bf16  g_aggT[NN * DIM];           // 32 MB : per-graph transpose [b][d][n]
__device__ bf16  g_qf[256 * DIM];            // QF[h*32+s][d] = q_h · Wk_h^T
__device__ bf16  g_wvo[DIM * 8 * DIM];       // 4 MB : Wvo[e][h*512+d] = sum_dh Wv[d][h64+dh] Wo[e][h64+dh]
__device__ float g_bvo[DIM];                 // bo + Wo·bv
__device__ bf16  g_wffT[DIM * DIM];          // = Wff (bf16)
__device__ float g_q[NS * DIM];              // scaled q (f32)
__device__ bf16  g_sc[BN * 256 * MAXN];      // 16.8 MB : scores bf16 [b][h*32+s][n]
__device__ bf16  g_cp[BN * NS * 8 * DIM];    // 16.8 MB : ctxpre [b*32+s][h*512+d]
__device__ float g_tmp[BN * NS * DIM];
__device__ float g_h1[BN * NS * DIM];
__device__ bf16  g_h1b[BN * NS * DIM];

__device__ inline float bf2f(unsigned short u) {
    union { unsigned int i; float f; } x; x.i = ((unsigned int)u) << 16; return x.f;
}

__device__ inline void gll16(const bf16* g, bf16* l) {
    __builtin_amdgcn_global_load_lds(
        (const __attribute__((address_space(1))) void*)g,
        (__attribute__((address_space(3))) void*)l, 16, 0, 0);
}

// ---------------- graph preprocessing ----------------
__global__ void k_zero() {
    int i = blockIdx.x * 256 + threadIdx.x;
    if (i < NN) { g_cnt[i] = 0; g_cur[i] = 0; }
}

__global__ void k_count(const int* __restrict__ dst) {
    int e = blockIdx.x * 256 + threadIdx.x;
    if (e < NE) atomicAdd(&g_cnt[dst[e]], 1);
}

__global__ void k_scan() {          // exclusive scan + dinv fused
    __shared__ int part[1024];
    int t = threadIdx.x;
    int base = t * 32;
    int loc[32]; int s = 0;
#pragma unroll
    for (int i = 0; i < 32; i++) { loc[i] = g_cnt[base + i]; s += loc[i]; }
    part[t] = s; __syncthreads();
    for (int o = 1; o < 1024; o <<= 1) {
        int v = (t >= o) ? part[t - o] : 0;
        __syncthreads();
        part[t] += v;
        __syncthreads();
    }
    int ex = (t == 0) ? 0 : part[t - 1];
#pragma unroll
    for (int i = 0; i < 32; i++) {
        g_off[base + i] = ex; ex += loc[i];
        g_dinv[base + i] = rsqrtf(1.0f + (float)loc[i]);
    }
    if (t == 1023) g_off[NN] = ex;
}

__global__ void k_fill(const int* __restrict__ src, const int* __restrict__ dst) {
    int e = blockIdx.x * 256 + threadIdx.x;
    if (e < NE) {
        int d = dst[e];
        int p = atomicAdd(&g_cur[d], 1);
        g_csr[g_off[d] + p] = src[e];
    }
}

// xb[i] = bf16(x[i] * dinv[node])
__global__ __launch_bounds__(256) void k_xb(const float* __restrict__ x) {
    long i = (long)(blockIdx.x * 256 + threadIdx.x) * 8;
    int node = (int)(i >> 9);
    float w = g_dinv[node];
    float4 a = *(const float4*)(x + i);
    float4 b = *(const float4*)(x + i + 4);
    float v[8] = {a.x, a.y, a.z, a.w, b.x, b.y, b.z, b.w};
    bf16x8 o;
#pragma unroll
    for (int j = 0; j < 8; j++) { bf16 t = __float2bfloat16(v[j] * w); o[j] = *(short*)&t; }
    *(bf16x8*)(g_xb + i) = o;
}

// agg[d] = bf16( dinv[d] * ( xb[d] + sum xb[src] ) )  (one wave per node, XCD-chunked)
__global__ __launch_bounds__(256) void k_gather() {
    int bid = blockIdx.x;
    int lb = (bid & 7) * 1024 + (bid >> 3);
    int wave = threadIdx.x >> 6, lane = threadIdx.x & 63;
    int node = lb * 4 + wave;

    bf16x8 sv = ((const bf16x8*)(g_xb + (long)node * DIM))[lane];
    float acc[8];
#pragma unroll
    for (int j = 0; j < 8; j++) acc[j] = bf2f((unsigned short)sv[j]);

    int e = g_off[node], e1 = g_off[node + 1];
    for (; e + 4 <= e1; e += 4) {
        int s0 = g_csr[e], s1 = g_csr[e + 1], s2 = g_csr[e + 2], s3 = g_csr[e + 3];
        bf16x8 r0 = ((const bf16x8*)(g_xb + (long)s0 * DIM))[lane];
        bf16x8 r1 = ((const bf16x8*)(g_xb + (long)s1 * DIM))[lane];
        bf16x8 r2 = ((const bf16x8*)(g_xb + (long)s2 * DIM))[lane];
        bf16x8 r3 = ((const bf16x8*)(g_xb + (long)s3 * DIM))[lane];
#pragma unroll
        for (int j = 0; j < 8; j++)
            acc[j] += (bf2f((unsigned short)r0[j]) + bf2f((unsigned short)r1[j]))
                    + (bf2f((unsigned short)r2[j]) + bf2f((unsigned short)r3[j]));
    }
    for (; e < e1; e++) {
        int s0 = g_csr[e];
        bf16x8 r0 = ((const bf16x8*)(g_xb + (long)s0 * DIM))[lane];
#pragma unroll
        for (int j = 0; j < 8; j++) acc[j] += bf2f((unsigned short)r0[j]);
    }
    float dd = g_dinv[node];
    bf16x8 o;
#pragma unroll
    for (int j = 0; j < 8; j++) { bf16 t = __float2bfloat16(acc[j] * dd); o[j] = *(short*)&t; }
    ((bf16x8*)(g_agg + (long)node * DIM))[lane] = o;
}

// per-graph transpose: aggT[b][d][n] = agg[b*512+n][d], 64x64 tiles
__global__ __launch_bounds__(256) void k_aggT() {
    __shared__ unsigned short L[64][72];
    int id = blockIdx.x;
    int b = id >> 6, t = id & 63;
    int n0 = (t & 7) * 64, d0 = (t >> 3) * 64;
    int tid = threadIdx.x;
    const unsigned short* src = (const unsigned short*)g_agg + ((long)b * 512 + n0) * 512 + d0;
#pragma unroll
    for (int p = 0; p < 2; p++) {
        int r = (tid >> 3) + 32 * p, c = (tid & 7) * 8;
        *(int4*)&L[r][c] = *(const int4*)(src + (long)r * 512 + c);
    }
    __syncthreads();
    unsigned short* dst = (unsigned short*)g_aggT + ((long)b * 512 + d0) * 512 + n0;
#pragma unroll
    for (int p = 0; p < 2; p++) {
        int dr = (tid >> 3) + 32 * p, c0 = (tid & 7) * 8;
        unsigned short tmp[8];
#pragma unroll
        for (int j = 0; j < 8; j++) tmp[j] = L[c0 + j][dr];
        *(int4*)(dst + (long)dr * 512 + c0) = *(int4*)tmp;
    }
}

// q[s][e] = (sum_d seed[s][d] * Wq[e][d]) / sqrt(DH)
__global__ void k_qproj(const float* __restrict__ seed, const float* __restrict__ Wq) {
    int i = blockIdx.x * 256 + threadIdx.x;        // 0 .. NS*DIM
    int s = i >> 9, e = i & 511;
    const float* sr = seed + s * DIM;
    const float* wr = Wq + e * DIM;
    float acc = 0.f;
    for (int d = 0; d < DIM; d += 4) {
        float4 a = *(const float4*)(sr + d);
        float4 b = *(const float4*)(wr + d);
        acc += a.x * b.x + a.y * b.y + a.z * b.z + a.w * b.w;
    }
    g_q[i] = acc * 0.125f;
}

// fused weight folding: QF, Wvo, bvo, wffT (block-range split)
__global__ __launch_bounds__(256) void k_fold(const float* __restrict__ Wk,
                                              const float* __restrict__ Wv,
                                              const float* __restrict__ Wo,
                                              const float* __restrict__ bo,
                                              const float* __restrict__ bv,
                                              const float* __restrict__ Wff) {
    int blk = blockIdx.x;
    if (blk < 512) {                         // QF[hs][d] = sum_dh q[s][h64+dh]*Wk[d][h64+dh]
        int i = blk * 256 + threadIdx.x;     // 0..131071
        int hs = i >> 9, d = i & 511;
        int h = hs >> 5, s = hs & 31;
        const float* qr = g_q + s * DIM + h * 64;
        const float* wr = Wk + d * DIM + h * 64;
        float acc = 0.f;
        for (int t2 = 0; t2 < 64; t2 += 4) {
            float4 a = *(const float4*)(qr + t2);
            float4 w = *(const float4*)(wr + t2);
            acc += a.x * w.x + a.y * w.y + a.z * w.z + a.w * w.w;
        }
        g_qf[i] = __float2bfloat16(acc);
    } else if (blk < 8704) {                 // Wvo[e][h*512+d]
        int j = (blk - 512) * 256 + threadIdx.x;   // 0..2097151
        int e = j >> 12, hd = j & 4095, h = hd >> 9, d = hd & 511;
        const float* vr = Wv + d * DIM + h * 64;
        const float* orow = Wo + e * DIM + h * 64;
        float acc = 0.f;
        for (int t2 = 0; t2 < 64; t2 += 4) {
            float4 a = *(const float4*)(vr + t2);
            float4 w = *(const float4*)(orow + t2);
            acc += a.x * w.x + a.y * w.y + a.z * w.z + a.w * w.w;
        }
        g_wvo[j] = __float2bfloat16(acc);
    } else if (blk < 8706) {                 // bvo[e] = bo[e] + sum_c bv[c]*Wo[e][c]
        int e = (blk - 8704) * 256 + threadIdx.x;
        float acc = bo[e];
        const float* orow = Wo + e * DIM;
        for (int c = 0; c < DIM; c++) acc += bv[c] * orow[c];
        g_bvo[e] = acc;
    } else {                                 // wffT
        int i = (blk - 8706) * 256 + threadIdx.x;
        g_wffT[i] = __float2bfloat16(Wff[i]);
    }
}

// ---------------- scores GEMM: g_sc[b][256][512] = QF[256][512] x agg_b^T ----------------
__global__ __launch_bounds__(256) void k_scores() {
    const bf16* A  = g_qf;
    const bf16* Bt = g_agg + (long)blockIdx.z * (MAXN * DIM);
    bf16* out = g_sc + (long)blockIdx.z * (256 * MAXN);

    __shared__ bf16 As[2][128 * 32];
    __shared__ bf16 Bs[2][128 * 32];
    int tid = threadIdx.x;
    int lane = tid & 63, wave = tid >> 6;
    int wr = wave >> 1, wc = wave & 1;
    long row0 = (long)blockIdx.x * 128, col0 = (long)blockIdx.y * 128;
    f32x4 acc[4][4];
#pragma unroll
    for (int i = 0; i < 4; i++)
#pragma unroll
        for (int j = 0; j < 4; j++) acc[i][j] = (f32x4){0.f, 0.f, 0.f, 0.f};
    int fr = lane & 15, fq = lane >> 4;
    int rchunk = (fq ^ ((fr >> 1) & 3)) * 8;

    int u0 = wave * 128 + lane;
    int s_row[2], s_col[2];
#pragma unroll
    for (int c = 0; c < 2; c++) {
        int u = u0 + c * 64;
        int row = u >> 2, cc = u & 3;
        s_row[c] = row;
        s_col[c] = (cc ^ ((row >> 1) & 3)) * 8;
    }

    auto stage = [&](int buf, int kt) {
#pragma unroll
        for (int c = 0; c < 2; c++)
            gll16(A + (row0 + s_row[c]) * DIM + kt + s_col[c], As[buf] + (u0 + c * 64) * 8);
#pragma unroll
        for (int c = 0; c < 2; c++)
            gll16(Bt + (col0 + s_row[c]) * DIM + kt + s_col[c], Bs[buf] + (u0 + c * 64) * 8);
    };

    stage(0, 0);
    __syncthreads();

    for (int kt = 0; kt < DIM; kt += 32) {
        int buf = (kt >> 5) & 1;
        if (kt + 32 < DIM) stage(buf ^ 1, kt + 32);
        bf16x8 af[4], bfv[4];
#pragma unroll
        for (int mi = 0; mi < 4; mi++)
            af[mi] = *(const bf16x8*)(As[buf] + (wr * 64 + mi * 16 + fr) * 32 + rchunk);
#pragma unroll
        for (int ni = 0; ni < 4; ni++)
            bfv[ni] = *(const bf16x8*)(Bs[buf] + (wc * 64 + ni * 16 + fr) * 32 + rchunk);
#pragma unroll
        for (int mi = 0; mi < 4; mi++)
#pragma unroll
            for (int ni = 0; ni < 4; ni++)
                acc[mi][ni] = __builtin_amdgcn_mfma_f32_16x16x32_bf16(af[mi], bfv[ni], acc[mi][ni], 0, 0, 0);
        __syncthreads();
    }
#pragma unroll
    for (int mi = 0; mi < 4; mi++)
#pragma unroll
        for (int ni = 0; ni < 4; ni++) {
            long col = col0 + wc * 64 + ni * 16 + fr;
#pragma unroll
            for (int r = 0; r < 4; r++) {
                long row = row0 + wr * 64 + mi * 16 + fq * 4 + r;
                out[row * MAXN + col] = __float2bfloat16(acc[mi][ni][r]);
            }
        }
}

// ---------------- softmax + PVpre: ctxpre[b*32+s][h*512 + dh*256 + d] ----------------
// grid: id = b*16 + h*2 + dh ; 256 thr (4 waves), each wave owns 64 d-cols
__global__ __launch_bounds__(256) void k_pv() {
    __shared__ bf16 Pl[32 * 512];            // swizzled P, 32 KB
    __shared__ bf16 Bs[2][256 * 32];         // aggT tiles [256 d][32 n], 16 KB each
    int id = blockIdx.x;
    int b = id >> 4, h = (id >> 1) & 7, dh = id & 1;
    int tid = threadIdx.x, lane = tid & 63, w = tid >> 6;
    int fr = lane & 15, fq = lane >> 4;

    const bf16* BT = g_aggT + (long)b * (DIM * MAXN) + (long)dh * (256 * MAXN);
    int srow[4], scol[4];
#pragma unroll
    for (int c = 0; c < 4; c++) {
        int u = tid + 256 * c;
        srow[c] = u >> 2;
        scol[c] = ((u & 3) ^ ((srow[c] >> 1) & 3)) * 8;
    }
    auto stage = [&](int buf, int kt) {
#pragma unroll
        for (int c = 0; c < 4; c++)
            gll16(BT + (long)srow[c] * MAXN + kt + scol[c], Bs[buf] + (tid + 256 * c) * 8);
    };
    stage(0, 0);                             // overlap with softmax

    // ---- softmax (4 waves x 8 rows), normalized bf16 P into swizzled LDS ----
    const unsigned short* scp = (const unsigned short*)g_sc + ((long)b * 256 + (long)h * 32) * MAXN;
#pragma unroll
    for (int r = 0; r < 8; r++) {
        int row = w * 8 + r;
        float v[8]; float m = -1e30f;
#pragma unroll
        for (int k = 0; k < 8; k++) { v[k] = bf2f(scp[row * MAXN + lane + 64 * k]); m = fmaxf(m, v[k]); }
#pragma unroll
        for (int o = 32; o > 0; o >>= 1) m = fmaxf(m, __shfl_xor(m, o));
        float sum = 0.f;
#pragma unroll
        for (int k = 0; k < 8; k++) { v[k] = __expf(v[k] - m); sum += v[k]; }
#pragma unroll
        for (int o = 32; o > 0; o >>= 1) sum += __shfl_xor(sum, o);
        float inv = 1.0f / sum;
#pragma unroll
        for (int k = 0; k < 8; k++) {
            int col = lane + 64 * k;
            int chunk = (col >> 3) ^ (row & 7);
            Pl[row * 512 + chunk * 8 + (col & 7)] = __float2bfloat16(v[k] * inv);
        }
    }
    __syncthreads();                         // P ready + stage(0) drained

    f32x4 acc[2][4];
#pragma unroll
    for (int i = 0; i < 2; i++)
#pragma unroll
        for (int j = 0; j < 4; j++) acc[i][j] = (f32x4){0.f, 0.f, 0.f, 0.f};

    for (int kt = 0; kt < MAXN; kt += 32) {
        int buf = (kt >> 5) & 1;
        if (kt + 32 < MAXN) stage(buf ^ 1, kt + 32);
        bf16x8 pa[2], vb[4];
#pragma unroll
        for (int mi = 0; mi < 2; mi++) {
            int pr = mi * 16 + fr;
            int slot = ((kt >> 3) + fq) ^ (pr & 7);
            pa[mi] = *(const bf16x8*)(Pl + pr * 512 + slot * 8);
        }
#pragma unroll
        for (int nf = 0; nf < 4; nf++) {
            int dr = w * 64 + nf * 16 + fr;
            vb[nf] = *(const bf16x8*)(Bs[buf] + dr * 32 + (fq ^ ((dr >> 1) & 3)) * 8);
        }
#pragma unroll
        for (int mi = 0; mi < 2; mi++)
#pragma unroll
            for (int nf = 0; nf < 4; nf++)
                acc[mi][nf] = __builtin_amdgcn_mfma_f32_16x16x32_bf16(pa[mi], vb[nf], acc[mi][nf], 0, 0, 0);
        __syncthreads();
    }
#pragma unroll
    for (int mi = 0; mi < 2; mi++)
#pragma unroll
        for (int nf = 0; nf < 4; nf++) {
            int d = w * 64 + nf * 16 + fr;
#pragma unroll
            for (int r = 0; r < 4; r++) {
                int s = mi * 16 + fq * 4 + r;
                g_cp[((long)b * NS + s) * 4096 + h * 512 + dh * 256 + d] =
                    __float2bfloat16(acc[mi][nf][r]);
            }
        }
}

// ---------------- 64x64-tile GEMM: out f32 = A[M][KD] x Bt[512][KD]^T + bias ----------------
// FFN=0: A=g_cp (KD=4096), Bt=g_wvo, bias=g_bvo   |  FFN=1: A=g_h1b (KD=512), Bt=g_wffT, bias=arg
template<int KD, bool FFN>
__global__ __launch_bounds__(256) void k_gemm64(const float* __restrict__ biasIn) {
    const bf16* A  = FFN ? g_h1b : g_cp;
    const bf16* Bt = FFN ? g_wffT : g_wvo;

    __shared__ bf16 As[2][64 * 32];
    __shared__ bf16 Bs[2][64 * 32];
    int tid = threadIdx.x;
    int lane = tid & 63, wave = tid >> 6;
    int wr = wave >> 1, wc = wave & 1;
    long row0 = (long)blockIdx.x * 64, col0 = (long)blockIdx.y * 64;
    f32x4 acc[2][2];
#pragma unroll
    for (int i = 0; i < 2; i++)
#pragma unroll
        for (int j = 0; j < 2; j++) acc[i][j] = (f32x4){0.f, 0.f, 0.f, 0.f};
    int fr = lane & 15, fq = lane >> 4;

    int srow = tid >> 2, scc = tid & 3;
    int scol = (scc ^ ((srow >> 1) & 3)) * 8;

    auto stage = [&](int buf, int kt) {
        gll16(A  + (row0 + srow) * KD + kt + scol, As[buf] + tid * 8);
        gll16(Bt + (col0 + srow) * KD + kt + scol, Bs[buf] + tid * 8);
    };

    stage(0, 0);
    __syncthreads();

    for (int kt = 0; kt < KD; kt += 32) {
        int buf = (kt >> 5) & 1;
        if (kt + 32 < KD) stage(buf ^ 1, kt + 32);
        bf16x8 af[2], bfv[2];
#pragma unroll
        for (int mi = 0; mi < 2; mi++) {
            int ar = wr * 32 + mi * 16 + fr;
            af[mi] = *(const bf16x8*)(As[buf] + ar * 32 + (fq ^ ((ar >> 1) & 3)) * 8);
        }
#pragma unroll
        for (int ni = 0; ni < 2; ni++) {
            int br = wc * 32 + ni * 16 + fr;
            bfv[ni] = *(const bf16x8*)(Bs[buf] + br * 32 + (fq ^ ((br >> 1) & 3)) * 8);
        }
#pragma unroll
        for (int mi = 0; mi < 2; mi++)
#pragma unroll
            for (int ni = 0; ni < 2; ni++)
                acc[mi][ni] = __builtin_amdgcn_mfma_f32_16x16x32_bf16(af[mi], bfv[ni], acc[mi][ni], 0, 0, 0);
        __syncthreads();
    }
    const float* bias = FFN ? biasIn : g_bvo;
#pragma unroll
    for (int mi = 0; mi < 2; mi++)
#pragma unroll
        for (int ni = 0; ni < 2; ni++) {
            long col = col0 + wc * 32 + ni * 16 + fr;
            float bv = bias[col];
#pragma unroll
            for (int r = 0; r < 4; r++) {
                long row = row0 + wr * 32 + mi * 16 + fq * 4 + r;
                g_tmp[row * DIM + col] = acc[mi][ni][r] + bv;
            }
        }
}

// ---------------- layernorms ----------------
__device__ inline float blockReduceSum(float v, float* red, int tid) {
#pragma unroll
    for (int o = 32; o > 0; o >>= 1) v += __shfl_xor(v, o);
    __syncthreads();
    if ((tid & 63) == 0) red[tid >> 6] = v;
    __syncthreads();
    return red[0] + red[1] + red[2] + red[3];
}

__global__ __launch_bounds__(256) void k_ln1(const float* __restrict__ seed,
                                             const float* __restrict__ gamma,
                                             const float* __restrict__ beta) {
    __shared__ float red[4];
    int r = blockIdx.x, t = threadIdx.x;
    int s = r & 31;
    long base = (long)r * DIM;
    float v0 = g_tmp[base + t] + seed[s * DIM + t];
    float v1 = g_tmp[base + 256 + t] + seed[s * DIM + 256 + t];
    float mean = blockReduceSum(v0 + v1, red, t) * (1.0f / DIM);
    float d0 = v0 - mean, d1 = v1 - mean;
    float var = blockReduceSum(d0 * d0 + d1 * d1, red, t) * (1.0f / DIM);
    float ri = rsqrtf(var + 1e-5f);
    float o0 = d0 * ri * gamma[t] + beta[t];
    float o1 = d1 * ri * gamma[256 + t] + beta[256 + t];
    g_h1[base + t] = o0; g_h1[base + 256 + t] = o1;
    g_h1b[base + t] = __float2bfloat16(o0);
    g_h1b[base + 256 + t] = __float2bfloat16(o1);
}

__global__ __launch_bounds__(256) void k_ln2(const float* __restrict__ gamma,
                                             const float* __restrict__ beta,
                                             float* __restrict__ out) {
    __shared__ float red[4];
    int r = blockIdx.x, t = threadIdx.x;
    long base = (long)r * DIM;
    float v0 = g_tmp[base + t] + g_h1[base + t];
    float v1 = g_tmp[base + 256 + t] + g_h1[base + 256 + t];
    float mean = blockReduceSum(v0 + v1, red, t) * (1.0f / DIM);
    float d0 = v0 - mean, d1 = v1 - mean;
    float var = blockReduceSum(d0 * d0 + d1 * d1, red, t) * (1.0f / DIM);
    float ri = rsqrtf(var + 1e-5f);
    out[base + t] = d0 * ri * gamma[t] + beta[t];
    out[base + 256 + t] = d1 * ri * gamma[256 + t] + beta[256 + t];
}

// ---------------- launch ----------------
extern "C" void kernel_launch(void* const* d_in, const int* in_sizes, int n_in,
                              void* d_out, int out_size, void* d_ws, size_t ws_size,
                              hipStream_t stream) {
    (void)in_sizes; (void)n_in; (void)out_size; (void)d_ws; (void)ws_size;
    const float* x    = (const float*)d_in[1];
    const int*   ei   = (const int*)d_in[2];
    const int*   esrc = ei;
    const int*   edst = ei + NE;
    const float* seed = (const float*)d_in[4];
    const float* Wk   = (const float*)d_in[5];
    const float* Wv   = (const float*)d_in[7];
    const float* bv   = (const float*)d_in[8];
    const float* Wq   = (const float*)d_in[9];
    const float* Wo   = (const float*)d_in[10];
    const float* bo   = (const float*)d_in[11];
    const float* Wff  = (const float*)d_in[12];
    const float* bff  = (const float*)d_in[13];
    const float* gh   = (const float*)d_in[14];
    const float* bh   = (const float*)d_in[15];
    const float* gz   = (const float*)d_in[16];
    const float* bz   = (const float*)d_in[17];
    float* out = (float*)d_out;

    k_zero <<<NN / 256, 256, 0, stream>>>();
    k_count<<<NE / 256, 256, 0, stream>>>(edst);
    k_scan <<<1, 1024, 0, stream>>>();
    k_fill <<<NE / 256, 256, 0, stream>>>(esrc, edst);
    k_xb   <<<(NN * DIM) / (256 * 8), 256, 0, stream>>>(x);
    k_gather<<<NN / 4, 256, 0, stream>>>();
    k_aggT <<<BN * 64, 256, 0, stream>>>();
    k_qproj<<<(NS * DIM) / 256, 256, 0, stream>>>(seed, Wq);
    k_fold <<<9730, 256, 0, stream>>>(Wk, Wv, Wo, bo, bv, Wff);

    dim3 gs(2, 4, BN);
    k_scores<<<gs, 256, 0, stream>>>();

    k_pv<<<BN * 16, 256, 0, stream>>>();

    dim3 g64(32, 8);
    k_gemm64<4096, false><<<g64, 256, 0, stream>>>(nullptr);
    k_ln1<<<BN * NS, 256, 0, stream>>>(seed, gh, bh);
    k_gemm64<512, true><<<g64, 256, 0, stream>>>(bff);
    k_ln2<<<BN * NS, 256, 0, stream>>>(gz, bz, out);
}

// Round 6
// 270.498 us; speedup vs baseline: 1.3859x; 1.3859x over previous
//
#include <hip/hip_runtime.h>
#include <hip/hip_bf16.h>

#define BN   64
#define MAXN 512
#define DIM  512
#define NH   8
#define NS   32
#define NN   32768      // BN*MAXN
#define NE   524288
#define MP   (2048 * 512)   // one partial slice

typedef __hip_bfloat16 bf16;
using bf16x8 = __attribute__((ext_vector_type(8))) short;   // 8 bf16 (4 VGPRs)
using f32x4  = __attribute__((ext_vector_type(4))) float;

// ---- persistent device scratch ----
__device__ int   g_cnt[NN];
__device__ int   g_cur[NN];
__device__ int   g_off[NN + 1];
__device__ int   g_csr[NE];
__device__ float g_dinv[NN];
__device__ bf16  g_xb[NN * DIM];             // 32 MB
__device__ bf16  g_agg[NN * DIM];            // 32 MB
__device__ bf16  g_aggT[NN * DIM];           // 32 MB [b][d][n]
__device__ bf16  g_qf[256 * DIM];            // QF[h*32+s][d]
__device__ bf16  g_wob[DIM * DIM];           // Wo bf16
__device__ bf16  g_wvb[DIM * DIM];           // Wv bf16
__device__ bf16  g_wvo[DIM * 8 * DIM];       // 4 MB [e][h*512+d]
__device__ float g_bvo[DIM];
__device__ bf16  g_wffT[DIM * DIM];
__device__ float g_q[NS * DIM];
__device__ bf16  g_sc[BN * 256 * MAXN];      // scores -> P (in-place softmax)
__device__ bf16  g_cp[BN * NS * 8 * DIM];    // ctxpre [b*32+s][h*512+dh*256+d]
__device__ float g_part[8 * MP];             // split-K partials (33.5 MB, reused)
__device__ float g_h1[BN * NS * DIM];
__device__ bf16  g_h1b[BN * NS * DIM];

__device__ inline float bf2f(unsigned short u) {
    union { unsigned int i; float f; } x; x.i = ((unsigned int)u) << 16; return x.f;
}

__device__ inline void gll16(const bf16* g, bf16* l) {
    __builtin_amdgcn_global_load_lds(
        (const __attribute__((address_space(1))) void*)g,
        (__attribute__((address_space(3))) void*)l, 16, 0, 0);
}

// ---------------- graph preprocessing ----------------
__global__ void k_zero() {
    int i = blockIdx.x * 256 + threadIdx.x;
    if (i < NN) { g_cnt[i] = 0; g_cur[i] = 0; }
}

__global__ void k_count(const int* __restrict__ dst) {
    int e = blockIdx.x * 256 + threadIdx.x;
    if (e < NE) atomicAdd(&g_cnt[dst[e]], 1);
}

__global__ void k_scan() {
    __shared__ int part[1024];
    int t = threadIdx.x;
    int base = t * 32;
    int loc[32]; int s = 0;
#pragma unroll
    for (int i = 0; i < 32; i++) { loc[i] = g_cnt[base + i]; s += loc[i]; }
    part[t] = s; __syncthreads();
    for (int o = 1; o < 1024; o <<= 1) {
        int v = (t >= o) ? part[t - o] : 0;
        __syncthreads();
        part[t] += v;
        __syncthreads();
    }
    int ex = (t == 0) ? 0 : part[t - 1];
#pragma unroll
    for (int i = 0; i < 32; i++) {
        g_off[base + i] = ex; ex += loc[i];
        g_dinv[base + i] = rsqrtf(1.0f + (float)loc[i]);
    }
    if (t == 1023) g_off[NN] = ex;
}

__global__ void k_fill(const int* __restrict__ src, const int* __restrict__ dst) {
    int e = blockIdx.x * 256 + threadIdx.x;
    if (e < NE) {
        int d = dst[e];
        int p = atomicAdd(&g_cur[d], 1);
        g_csr[g_off[d] + p] = src[e];
    }
}

__global__ __launch_bounds__(256) void k_xb(const float* __restrict__ x) {
    long i = (long)(blockIdx.x * 256 + threadIdx.x) * 8;
    int node = (int)(i >> 9);
    float w = g_dinv[node];
    float4 a = *(const float4*)(x + i);
    float4 b = *(const float4*)(x + i + 4);
    float v[8] = {a.x, a.y, a.z, a.w, b.x, b.y, b.z, b.w};
    bf16x8 o;
#pragma unroll
    for (int j = 0; j < 8; j++) { bf16 t = __float2bfloat16(v[j] * w); o[j] = *(short*)&t; }
    *(bf16x8*)(g_xb + i) = o;
}

__global__ __launch_bounds__(256) void k_gather() {
    int bid = blockIdx.x;
    int lb = (bid & 7) * 1024 + (bid >> 3);
    int wave = threadIdx.x >> 6, lane = threadIdx.x & 63;
    int node = lb * 4 + wave;

    bf16x8 sv = ((const bf16x8*)(g_xb + (long)node * DIM))[lane];
    float acc[8];
#pragma unroll
    for (int j = 0; j < 8; j++) acc[j] = bf2f((unsigned short)sv[j]);

    int e = g_off[node], e1 = g_off[node + 1];
    for (; e + 4 <= e1; e += 4) {
        int s0 = g_csr[e], s1 = g_csr[e + 1], s2 = g_csr[e + 2], s3 = g_csr[e + 3];
        bf16x8 r0 = ((const bf16x8*)(g_xb + (long)s0 * DIM))[lane];
        bf16x8 r1 = ((const bf16x8*)(g_xb + (long)s1 * DIM))[lane];
        bf16x8 r2 = ((const bf16x8*)(g_xb + (long)s2 * DIM))[lane];
        bf16x8 r3 = ((const bf16x8*)(g_xb + (long)s3 * DIM))[lane];
#pragma unroll
        for (int j = 0; j < 8; j++)
            acc[j] += (bf2f((unsigned short)r0[j]) + bf2f((unsigned short)r1[j]))
                    + (bf2f((unsigned short)r2[j]) + bf2f((unsigned short)r3[j]));
    }
    for (; e < e1; e++) {
        int s0 = g_csr[e];
        bf16x8 r0 = ((const bf16x8*)(g_xb + (long)s0 * DIM))[lane];
#pragma unroll
        for (int j = 0; j < 8; j++) acc[j] += bf2f((unsigned short)r0[j]);
    }
    float dd = g_dinv[node];
    bf16x8 o;
#pragma unroll
    for (int j = 0; j < 8; j++) { bf16 t = __float2bfloat16(acc[j] * dd); o[j] = *(short*)&t; }
    ((bf16x8*)(g_agg + (long)node * DIM))[lane] = o;
}

// per-graph transpose: aggT[b][d][n] = agg[b*512+n][d]
__global__ __launch_bounds__(256) void k_aggT() {
    __shared__ unsigned short L[64][72];
    int id = blockIdx.x;
    int b = id >> 6, t = id & 63;
    int n0 = (t & 7) * 64, d0 = (t >> 3) * 64;
    int tid = threadIdx.x;
    const unsigned short* src = (const unsigned short*)g_agg + ((long)b * 512 + n0) * 512 + d0;
#pragma unroll
    for (int p = 0; p < 2; p++) {
        int r = (tid >> 3) + 32 * p, c = (tid & 7) * 8;
        *(int4*)&L[r][c] = *(const int4*)(src + (long)r * 512 + c);
    }
    __syncthreads();
    unsigned short* dst = (unsigned short*)g_aggT + ((long)b * 512 + d0) * 512 + n0;
#pragma unroll
    for (int p = 0; p < 2; p++) {
        int dr = (tid >> 3) + 32 * p, c0 = (tid & 7) * 8;
        unsigned short tmp[8];
#pragma unroll
        for (int j = 0; j < 8; j++) tmp[j] = L[c0 + j][dr];
        *(int4*)(dst + (long)dr * 512 + c0) = *(int4*)tmp;
    }
}

__global__ void k_qproj(const float* __restrict__ seed, const float* __restrict__ Wq) {
    int i = blockIdx.x * 256 + threadIdx.x;
    int s = i >> 9, e = i & 511;
    const float* sr = seed + s * DIM;
    const float* wr = Wq + e * DIM;
    float a0 = 0.f, a1 = 0.f;
    for (int d = 0; d < DIM; d += 8) {
        float4 a = *(const float4*)(sr + d);
        float4 b = *(const float4*)(wr + d);
        float4 c = *(const float4*)(sr + d + 4);
        float4 w = *(const float4*)(wr + d + 4);
        a0 += a.x * b.x + a.y * b.y + a.z * b.z + a.w * b.w;
        a1 += c.x * w.x + c.y * w.y + c.z * w.z + c.w * w.w;
    }
    g_q[i] = (a0 + a1) * 0.125f;
}

// ---------------- weight prep ----------------
__global__ __launch_bounds__(256) void k_cvt(const float* __restrict__ Wo,
                                             const float* __restrict__ Wv,
                                             const float* __restrict__ Wff) {
    long t = blockIdx.x * 256 + threadIdx.x;       // 0..98303
    const float* src; bf16* dst; long off;
    if (t < 32768)      { src = Wo;  dst = g_wob;  off = t; }
    else if (t < 65536) { src = Wv;  dst = g_wvb;  off = t - 32768; }
    else                { src = Wff; dst = g_wffT; off = t - 65536; }
    long i = off * 8;
    float4 a = *(const float4*)(src + i);
    float4 b = *(const float4*)(src + i + 4);
    float v[8] = {a.x, a.y, a.z, a.w, b.x, b.y, b.z, b.w};
    bf16x8 o;
#pragma unroll
    for (int j = 0; j < 8; j++) { bf16 q = __float2bfloat16(v[j]); o[j] = *(short*)&q; }
    *(bf16x8*)(dst + i) = o;
}

// QF[hs][d] = sum_dh q[s][h64+dh] * Wk[d][h64+dh]
__global__ __launch_bounds__(256) void k_qf(const float* __restrict__ Wk) {
    int i = blockIdx.x * 256 + threadIdx.x;
    int hs = i >> 9, d = i & 511;
    int h = hs >> 5, s = hs & 31;
    const float* qr = g_q + s * DIM + h * 64;
    const float* wr = Wk + d * DIM + h * 64;
    float a0 = 0.f, a1 = 0.f;
    for (int t2 = 0; t2 < 64; t2 += 8) {
        float4 a = *(const float4*)(qr + t2);
        float4 w = *(const float4*)(wr + t2);
        float4 c = *(const float4*)(qr + t2 + 4);
        float4 u = *(const float4*)(wr + t2 + 4);
        a0 += a.x * w.x + a.y * w.y + a.z * w.z + a.w * w.w;
        a1 += c.x * u.x + c.y * u.y + c.z * u.z + c.w * u.w;
    }
    g_qf[i] = __float2bfloat16(a0 + a1);
}

// bvo[e] = bo[e] + sum_c bv[c] * Wo[e][c]
__global__ __launch_bounds__(256) void k_bvo(const float* __restrict__ bo,
                                             const float* __restrict__ bv,
                                             const float* __restrict__ Wo) {
    int e = blockIdx.x * 256 + threadIdx.x;
    const float* orow = Wo + (long)e * DIM;
    float a0 = 0.f, a1 = 0.f;
    for (int c = 0; c < DIM; c += 8) {
        float4 a = *(const float4*)(bv + c);
        float4 w = *(const float4*)(orow + c);
        float4 x = *(const float4*)(bv + c + 4);
        float4 u = *(const float4*)(orow + c + 4);
        a0 += a.x * w.x + a.y * w.y + a.z * w.z + a.w * w.w;
        a1 += x.x * u.x + x.y * u.y + x.z * u.z + x.w * u.w;
    }
    g_bvo[e] = bo[e] + a0 + a1;
}

// ---------------- shared 128x128 MFMA GEMM core (swizzled gll + dbuf) ----------------
__device__ __forceinline__ void gemm128(const bf16* __restrict__ A, long lda,
                                        const bf16* __restrict__ Bt, long ldb,
                                        long row0, long col0, int kbeg, int kend,
                                        bf16 (*As)[128 * 32], bf16 (*Bs)[128 * 32],
                                        f32x4 acc[4][4]) {
    int tid = threadIdx.x;
    int lane = tid & 63, wave = tid >> 6;
    int wr = wave >> 1, wc = wave & 1;
    int fr = lane & 15, fq = lane >> 4;
    int rchunk = (fq ^ ((fr >> 1) & 3)) * 8;
    int u0 = wave * 128 + lane;
    int sr0 = u0 >> 2, sc0 = ((u0 & 3) ^ ((sr0 >> 1) & 3)) * 8;
    int u1 = u0 + 64;
    int sr1 = u1 >> 2, sc1 = ((u1 & 3) ^ ((sr1 >> 1) & 3)) * 8;

    auto stage = [&](int buf, int kt) {
        gll16(A + (row0 + sr0) * lda + kt + sc0, As[buf] + u0 * 8);
        gll16(A + (row0 + sr1) * lda + kt + sc1, As[buf] + u1 * 8);
        gll16(Bt + (col0 + sr0) * ldb + kt + sc0, Bs[buf] + u0 * 8);
        gll16(Bt + (col0 + sr1) * ldb + kt + sc1, Bs[buf] + u1 * 8);
    };

    stage(0, kbeg);
    __syncthreads();
    for (int kt = kbeg; kt < kend; kt += 32) {
        int buf = ((kt - kbeg) >> 5) & 1;
        if (kt + 32 < kend) stage(buf ^ 1, kt + 32);
        bf16x8 af[4], bfv[4];
#pragma unroll
        for (int mi = 0; mi < 4; mi++)
            af[mi] = *(const bf16x8*)(As[buf] + (wr * 64 + mi * 16 + fr) * 32 + rchunk);
#pragma unroll
        for (int ni = 0; ni < 4; ni++)
            bfv[ni] = *(const bf16x8*)(Bs[buf] + (wc * 64 + ni * 16 + fr) * 32 + rchunk);
#pragma unroll
        for (int mi = 0; mi < 4; mi++)
#pragma unroll
            for (int ni = 0; ni < 4; ni++)
                acc[mi][ni] = __builtin_amdgcn_mfma_f32_16x16x32_bf16(af[mi], bfv[ni], acc[mi][ni], 0, 0, 0);
        __syncthreads();
    }
}

#define GEMM_PROLOGUE                                        \
    __shared__ bf16 As[2][128 * 32];                         \
    __shared__ bf16 Bs[2][128 * 32];                         \
    f32x4 acc[4][4];                                         \
    _Pragma("unroll")                                        \
    for (int i = 0; i < 4; i++)                              \
        _Pragma("unroll")                                    \
        for (int j = 0; j < 4; j++) acc[i][j] = (f32x4){0.f, 0.f, 0.f, 0.f}; \
    int lane = threadIdx.x & 63, wave = threadIdx.x >> 6;    \
    int wr = wave >> 1, wc = wave & 1;                       \
    int fr = lane & 15, fq = lane >> 4;

// Wvo[e][h*512+d] = sum_k Wo[e][h64+k] * Wv[d][h64+k]  (batched per head, K=64)
__global__ __launch_bounds__(256) void k_wvo() {
    GEMM_PROLOGUE
    int h = blockIdx.z;
    long row0 = (long)blockIdx.x * 128, col0 = (long)blockIdx.y * 128;
    gemm128(g_wob, DIM, g_wvb, DIM, row0, col0, h * 64, h * 64 + 64, As, Bs, acc);
#pragma unroll
    for (int mi = 0; mi < 4; mi++)
#pragma unroll
        for (int ni = 0; ni < 4; ni++) {
            long col = col0 + wc * 64 + ni * 16 + fr;
#pragma unroll
            for (int r = 0; r < 4; r++) {
                long row = row0 + wr * 64 + mi * 16 + fq * 4 + r;
                g_wvo[row * 4096 + h * 512 + col] = __float2bfloat16(acc[mi][ni][r]);
            }
        }
}

// scores[b][hs][n] = QF[hs][:] . agg_b[n][:]
__global__ __launch_bounds__(256) void k_scores() {
    GEMM_PROLOGUE
    int b = blockIdx.z;
    long row0 = (long)blockIdx.x * 128, col0 = (long)blockIdx.y * 128;
    gemm128(g_qf, DIM, g_agg + (long)b * (MAXN * DIM), DIM, row0, col0, 0, DIM, As, Bs, acc);
    bf16* out = g_sc + (long)b * (256 * MAXN);
#pragma unroll
    for (int mi = 0; mi < 4; mi++)
#pragma unroll
        for (int ni = 0; ni < 4; ni++) {
            long col = col0 + wc * 64 + ni * 16 + fr;
#pragma unroll
            for (int r = 0; r < 4; r++) {
                long row = row0 + wr * 64 + mi * 16 + fq * 4 + r;
                out[row * MAXN + col] = __float2bfloat16(acc[mi][ni][r]);
            }
        }
}

// in-place row softmax on g_sc (16384 rows of 512)
__global__ __launch_bounds__(256) void k_soft() {
    int w = threadIdx.x >> 6, lane = threadIdx.x & 63;
    unsigned short* base = (unsigned short*)g_sc + ((long)blockIdx.x * 16 + w * 4) * MAXN;
#pragma unroll
    for (int r = 0; r < 4; r++) {
        unsigned short* row = base + (long)r * MAXN;
        float v[8]; float m = -1e30f;
#pragma unroll
        for (int k = 0; k < 8; k++) { v[k] = bf2f(row[lane + 64 * k]); m = fmaxf(m, v[k]); }
#pragma unroll
        for (int o = 32; o > 0; o >>= 1) m = fmaxf(m, __shfl_xor(m, o));
        float sum = 0.f;
#pragma unroll
        for (int k = 0; k < 8; k++) { v[k] = __expf(v[k] - m); sum += v[k]; }
#pragma unroll
        for (int o = 32; o > 0; o >>= 1) sum += __shfl_xor(sum, o);
        float inv = 1.0f / sum;
#pragma unroll
        for (int k = 0; k < 8; k++) {
            bf16 t = __float2bfloat16(v[k] * inv);
            row[lane + 64 * k] = *(unsigned short*)&t;
        }
    }
}

// ctxpre: per (b,dh): C[hs][d] = P_b[hs][:] . aggT_b[dh*256+d][:]   (M=256,N=256,K=512)
__global__ __launch_bounds__(256) void k_pvg() {
    GEMM_PROLOGUE
    int z = blockIdx.z, b = z >> 1, dh = z & 1;
    long row0 = (long)blockIdx.x * 128, col0 = (long)blockIdx.y * 128;
    gemm128(g_sc + (long)b * (256 * MAXN), MAXN,
            g_aggT + (long)b * (DIM * MAXN) + (long)dh * (256 * MAXN), MAXN,
            row0, col0, 0, MAXN, As, Bs, acc);
#pragma unroll
    for (int mi = 0; mi < 4; mi++)
#pragma unroll
        for (int ni = 0; ni < 4; ni++) {
            long col = col0 + wc * 64 + ni * 16 + fr;
#pragma unroll
            for (int r = 0; r < 4; r++) {
                long row = row0 + wr * 64 + mi * 16 + fq * 4 + r;   // hs
                g_cp[((long)b * NS + (row & 31)) * 4096 + (row >> 5) * 512 + dh * 256 + col] =
                    __float2bfloat16(acc[mi][ni][r]);
            }
        }
}

// attn_out partials: A=g_cp [2048][4096], Bt=g_wvo [512][4096], 8-way split-K
__global__ __launch_bounds__(256) void k_vo() {
    GEMM_PROLOGUE
    int z = blockIdx.z;
    long row0 = (long)blockIdx.x * 128, col0 = (long)blockIdx.y * 128;
    gemm128(g_cp, 4096, g_wvo, 4096, row0, col0, z * 512, z * 512 + 512, As, Bs, acc);
    float* out = g_part + (long)z * MP;
#pragma unroll
    for (int mi = 0; mi < 4; mi++)
#pragma unroll
        for (int ni = 0; ni < 4; ni++) {
            long col = col0 + wc * 64 + ni * 16 + fr;
#pragma unroll
            for (int r = 0; r < 4; r++) {
                long row = row0 + wr * 64 + mi * 16 + fq * 4 + r;
                out[row * DIM + col] = acc[mi][ni][r];
            }
        }
}

// FFN partials: A=g_h1b [2048][512], Bt=g_wffT [512][512], 4-way split-K
__global__ __launch_bounds__(256) void k_ffn() {
    GEMM_PROLOGUE
    int z = blockIdx.z;
    long row0 = (long)blockIdx.x * 128, col0 = (long)blockIdx.y * 128;
    gemm128(g_h1b, DIM, g_wffT, DIM, row0, col0, z * 128, z * 128 + 128, As, Bs, acc);
    float* out = g_part + (long)z * MP;
#pragma unroll
    for (int mi = 0; mi < 4; mi++)
#pragma unroll
        for (int ni = 0; ni < 4; ni++) {
            long col = col0 + wc * 64 + ni * 16 + fr;
#pragma unroll
            for (int r = 0; r < 4; r++) {
                long row = row0 + wr * 64 + mi * 16 + fq * 4 + r;
                out[row * DIM + col] = acc[mi][ni][r];
            }
        }
}

// ---------------- layernorms (fused split-K reduction + bias) ----------------
__device__ inline float blockReduceSum(float v, float* red, int tid) {
#pragma unroll
    for (int o = 32; o > 0; o >>= 1) v += __shfl_xor(v, o);
    __syncthreads();
    if ((tid & 63) == 0) red[tid >> 6] = v;
    __syncthreads();
    return red[0] + red[1] + red[2] + red[3];
}

__global__ __launch_bounds__(256) void k_ln1(const float* __restrict__ seed,
                                             const float* __restrict__ gamma,
                                             const float* __restrict__ beta) {
    __shared__ float red[4];
    int r = blockIdx.x, t = threadIdx.x;
    int s = r & 31;
    long base = (long)r * DIM;
    float v0 = seed[s * DIM + t] + g_bvo[t];
    float v1 = seed[s * DIM + 256 + t] + g_bvo[256 + t];
#pragma unroll
    for (int z = 0; z < 8; z++) {
        v0 += g_part[(long)z * MP + base + t];
        v1 += g_part[(long)z * MP + base + 256 + t];
    }
    float mean = blockReduceSum(v0 + v1, red, t) * (1.0f / DIM);
    float d0 = v0 - mean, d1 = v1 - mean;
    float var = blockReduceSum(d0 * d0 + d1 * d1, red, t) * (1.0f / DIM);
    float ri = rsqrtf(var + 1e-5f);
    float o0 = d0 * ri * gamma[t] + beta[t];
    float o1 = d1 * ri * gamma[256 + t] + beta[256 + t];
    g_h1[base + t] = o0; g_h1[base + 256 + t] = o1;
    g_h1b[base + t] = __float2bfloat16(o0);
    g_h1b[base + 256 + t] = __float2bfloat16(o1);
}

__global__ __launch_bounds__(256) void k_ln2(const float* __restrict__ gamma,
                                             const float* __restrict__ beta,
                                             const float* __restrict__ bff,
                                             float* __restrict__ out) {
    __shared__ float red[4];
    int r = blockIdx.x, t = threadIdx.x;
    long base = (long)r * DIM;
    float v0 = g_h1[base + t] + bff[t];
    float v1 = g_h1[base + 256 + t] + bff[256 + t];
#pragma unroll
    for (int z = 0; z < 4; z++) {
        v0 += g_part[(long)z * MP + base + t];
        v1 += g_part[(long)z * MP + base + 256 + t];
    }
    float mean = blockReduceSum(v0 + v1, red, t) * (1.0f / DIM);
    float d0 = v0 - mean, d1 = v1 - mean;
    float var = blockReduceSum(d0 * d0 + d1 * d1, red, t) * (1.0f / DIM);
    float ri = rsqrtf(var + 1e-5f);
    out[base + t] = d0 * ri * gamma[t] + beta[t];
    out[base + 256 + t] = d1 * ri * gamma[256 + t] + beta[256 + t];
}

// ---------------- launch ----------------
extern "C" void kernel_launch(void* const* d_in, const int* in_sizes, int n_in,
                              void* d_out, int out_size, void* d_ws, size_t ws_size,
                              hipStream_t stream) {
    (void)in_sizes; (void)n_in; (void)out_size; (void)d_ws; (void)ws_size;
    const float* x    = (const float*)d_in[1];
    const int*   ei   = (const int*)d_in[2];
    const int*   esrc = ei;
    const int*   edst = ei + NE;
    const float* seed = (const float*)d_in[4];
    const float* Wk   = (const float*)d_in[5];
    const float* Wv   = (const float*)d_in[7];
    const float* bv   = (const float*)d_in[8];
    const float* Wq   = (const float*)d_in[9];
    const float* Wo   = (const float*)d_in[10];
    const float* bo   = (const float*)d_in[11];
    const float* Wff  = (const float*)d_in[12];
    const float* bff  = (const float*)d_in[13];
    const float* gh   = (const float*)d_in[14];
    const float* bh   = (const float*)d_in[15];
    const float* gz   = (const float*)d_in[16];
    const float* bz   = (const float*)d_in[17];
    float* out = (float*)d_out;

    k_zero <<<NN / 256, 256, 0, stream>>>();
    k_count<<<NE / 256, 256, 0, stream>>>(edst);
    k_scan <<<1, 1024, 0, stream>>>();
    k_fill <<<NE / 256, 256, 0, stream>>>(esrc, edst);
    k_xb   <<<(NN * DIM) / (256 * 8), 256, 0, stream>>>(x);
    k_gather<<<NN / 4, 256, 0, stream>>>();
    k_aggT <<<BN * 64, 256, 0, stream>>>();
    k_qproj<<<(NS * DIM) / 256, 256, 0, stream>>>(seed, Wq);
    k_cvt  <<<384, 256, 0, stream>>>(Wo, Wv, Wff);
    k_qf   <<<512, 256, 0, stream>>>(Wk);
    k_wvo  <<<dim3(4, 4, 8), 256, 0, stream>>>();
    k_bvo  <<<2, 256, 0, stream>>>(bo, bv, Wo);

    k_scores<<<dim3(2, 4, BN), 256, 0, stream>>>();
    k_soft  <<<1024, 256, 0, stream>>>();
    k_pvg   <<<dim3(2, 2, BN * 2), 256, 0, stream>>>();

    k_vo <<<dim3(16, 4, 8), 256, 0, stream>>>();
    k_ln1<<<BN * NS, 256, 0, stream>>>(seed, gh, bh);
    k_ffn<<<dim3(16, 4, 4), 256, 0, stream>>>();
    k_ln2<<<BN * NS, 256, 0, stream>>>(gz, bz, bff, out);
}